// Round 4
// baseline (250.198 us; speedup 1.0000x reference)
//
#include <hip/hip_runtime.h>
#include <stdint.h>

#define PR1 73856093u
#define PR2 19349663u
#define PR3 83492791u
#define PR4 2654435761u
#define GS  32      // chunks per scan group
#define PPT 4       // points per thread per turn-round in k_scatter

// Branch-free uniform-divisor mod: q = floor(h * (1/d)) via double (exact for
// h < 2^32), one conditional fixup.
__device__ __forceinline__ uint32_t fastmod(uint32_t h, uint32_t d, double inv) {
    uint32_t q = (uint32_t)((double)h * inv);
    int32_t r = (int32_t)(h - q * d);
    if (r >= (int32_t)d) r -= d;
    if (r < 0) r += d;
    return (uint32_t)r;
}

// K1: bucket per point (written as float), per-chunk histogram -> chunk_hist[c][b].
// batch_id via an incremental pointer: i increases by blockDim each iteration
// and seps is sorted, so the while-advance costs amortized <=B LDS reads total.
__global__ void k_bucket_hist(const float* __restrict__ coords,
                              const int* __restrict__ seps, int B,
                              const int* __restrict__ hash_op_p,
                              int N, int NB, int chunk, double invNB,
                              float* __restrict__ out_bucket,
                              int* __restrict__ chunk_hist) {
    extern __shared__ int hist[];          // NB ints
    __shared__ int s_seps[1024];
    const int tid = threadIdx.x;
    for (int i = tid; i < NB; i += blockDim.x) hist[i] = 0;
    const int Bc = B < 1024 ? B : 1024;
    for (int j = tid; j < Bc; j += blockDim.x) s_seps[j] = seps[j];
    __syncthreads();

    const uint32_t hop = (uint32_t)hash_op_p[0];
    const int start = blockIdx.x * chunk;
    const int end   = min(start + chunk, N);
    int bid = 0;                            // running searchsorted-right pointer
    for (int i = start + tid; i < end; i += blockDim.x) {
        while (bid < B) {
            const int sv = (bid < 1024) ? s_seps[bid] : seps[bid];
            if (sv <= i) bid++; else break;
        }
        const float x = coords[3 * (size_t)i + 0];
        const float y = coords[3 * (size_t)i + 1];
        const float z = coords[3 * (size_t)i + 2];
        const uint32_t vx = (uint32_t)(int32_t)floorf(x);
        const uint32_t vy = (uint32_t)(int32_t)floorf(y);
        const uint32_t vz = (uint32_t)(int32_t)floorf(z);
        uint32_t h = vx * PR1 ^ vy * PR2 ^ vz * PR3 ^ ((uint32_t)bid * PR4);
        h += hop;
        const uint32_t b = fastmod(h, (uint32_t)NB, invNB);
        out_bucket[i] = (float)b;
        atomicAdd(&hist[(int)b], 1);
    }
    __syncthreads();
    int* dst = chunk_hist + (size_t)blockIdx.x * NB;
    for (int i = tid; i < NB; i += blockDim.x) dst[i] = hist[i];
}

// K2a: per bucket, exclusive scan within each group of GS chunks (in place);
// group totals -> Sg[g][b]. Parallel over G x NB columns, coalesced.
__global__ void k_scan_group(int* __restrict__ ch, int* __restrict__ Sg,
                             int C, int NB) {
    const int b = blockIdx.x * blockDim.x + threadIdx.x;
    if (b >= NB) return;
    const int g  = blockIdx.y;
    const int c0 = g * GS;
    const int c1 = min(c0 + GS, C);
    int run = 0;
    for (int c = c0; c < c1; c++) {
        const size_t idx = (size_t)c * NB + b;
        const int v = ch[idx];
        ch[idx] = run;
        run += v;
    }
    Sg[(size_t)g * NB + b] = run;
}

// K2b: exclusive scan over group totals (in place); total -> counts (float).
__global__ void k_scan_tops(int* __restrict__ Sg, int G, int NB,
                            float* __restrict__ out_counts) {
    const int b = blockIdx.x * blockDim.x + threadIdx.x;
    if (b >= NB) return;
    int run = 0;
    for (int g = 0; g < G; g++) {
        const size_t idx = (size_t)g * NB + b;
        const int v = Sg[idx];
        Sg[idx] = run;
        run += v;
    }
    out_counts[b] = (float)run;
}

// Zero only the unwritten slots [min(count,512), 512) of each bucket.
__global__ void k_gaps(const float* __restrict__ counts, float* __restrict__ out) {
    const int b = blockIdx.x;
    const int cnt = (int)counts[b];
    const int c0 = cnt < 512 ? cnt : 512;
    for (int j = c0 + (int)threadIdx.x; j < 512; j += (int)blockDim.x) {
        float* p = out + ((size_t)b * 512 + j) * 3;
        p[0] = 0.f; p[1] = 0.f; p[2] = 0.f;
    }
}

// K3: stable within-bucket rank (arrival order) + scatter.
// Per wave sub-batch: one 64-iter loop; per iteration the ballot column is
// UNIFORM, so rank/cnt/leader are computed on the scalar unit and delivered
// to lane j as one packed int via a single cndmask.
__global__ __launch_bounds__(256, 4)
void k_scatter(const float* __restrict__ coords,
               const float* __restrict__ bucket_f,
               const int* __restrict__ ch,
               const int* __restrict__ Sg,
               int N, int NB, int chunk,
               float* __restrict__ out_sc) {
    extern __shared__ int hist[];          // NB running counters
    const int tid = threadIdx.x;
    const int c = blockIdx.x;
    const int g = c / GS;
    const int* r1 = ch + (size_t)c * NB;
    const int* r2 = Sg + (size_t)g * NB;
    for (int i = tid; i < NB; i += blockDim.x) hist[i] = r1[i] + r2[i];
    __syncthreads();

    const int start = c * chunk;
    const int end   = min(start + chunk, N);
    const int len   = end > start ? end - start : 0;
    const int per_round = (int)blockDim.x * PPT;     // 1024
    const int rounds = (len + per_round - 1) / per_round;
    const int lane = tid & 63;
    const int wv   = tid >> 6;
    const int nw   = (int)blockDim.x >> 6;

    for (int rd = 0; rd < rounds; rd++) {
        const int wbase = start + rd * per_round + wv * (64 * PPT);
        int bs[PPT], pk[PPT];
        float cx[PPT], cy[PPT], cz[PPT];

        #pragma unroll
        for (int s = 0; s < PPT; s++) {
            const int i = wbase + s * 64 + lane;
            const bool v = (i < end);
            bs[s] = v ? (int)bucket_f[i] : -1;
            cx[s] = v ? coords[3 * (size_t)i + 0] : 0.f;
            cy[s] = v ? coords[3 * (size_t)i + 1] : 0.f;
            cz[s] = v ? coords[3 * (size_t)i + 2] : 0.f;
        }

        // Match: pk[s] = rank<<16 | cnt<<8 | leader for this lane's group.
        #pragma unroll
        for (int s = 0; s < PPT; s++) {
            const int b = bs[s];
            int pack = 0;
            #pragma unroll
            for (int j = 0; j < 64; j++) {
                const int bj = __builtin_amdgcn_readlane(b, j);
                const unsigned long long col = __ballot(b == bj);   // uniform
                const int cnt    = __builtin_popcountll(col);
                const int leader = (int)__builtin_ctzll(col);
                const int rnk    = __builtin_popcountll(col & (((unsigned long long)1 << j) - 1ull));
                const int p      = (rnk << 16) | (cnt << 8) | leader;
                pack = (lane == j) ? p : pack;
            }
            pk[s] = pack;
        }

        // Wave turn loop: arrival order = wave 0..nw-1, sub-batch 0..PPT-1.
        int basev[PPT];
        for (int w = 0; w < nw; w++) {
            if (wv == w) {
                #pragma unroll
                for (int s = 0; s < PPT; s++) {
                    const int leader = pk[s] & 0x3f;
                    const int cnt    = (pk[s] >> 8) & 0x7f;
                    int old = 0;
                    if (bs[s] >= 0 && lane == leader)
                        old = atomicAdd(&hist[bs[s]], cnt);
                    basev[s] = __shfl(old, leader, 64);
                }
            }
            __syncthreads();
        }

        #pragma unroll
        for (int s = 0; s < PPT; s++) {
            if (bs[s] >= 0) {
                const int r = basev[s] + (pk[s] >> 16);
                if (r < 512) {
                    float* p = out_sc + ((size_t)bs[s] * 512 + r) * 3;
                    p[0] = cx[s]; p[1] = cy[s]; p[2] = cz[s];
                }
            }
        }
    }
}

extern "C" void kernel_launch(void* const* d_in, const int* in_sizes, int n_in,
                              void* d_out, int out_size, void* d_ws, size_t ws_size,
                              hipStream_t stream) {
    const float* coords  = (const float*)d_in[0];
    const int*   seps    = (const int*)d_in[1];
    const int*   hash_op = (const int*)d_in[2];

    const int N = in_sizes[0] / 3;
    const int B = in_sizes[1];
    const int pad_to = ((N + 511) / 512) * 512;
    const int NB = pad_to / 512;

    float* out        = (float*)d_out;
    float* out_counts = out + (size_t)pad_to * 3;
    float* out_bucket = out_counts + NB;

    const size_t rowbytes = (size_t)NB * sizeof(int);
    const long rows = (long)(ws_size / rowbytes);
    int C = 1024;
    while (C > 1 && (long)(C + (C + GS - 1) / GS) > rows) C--;
    if (C < 1) C = 1;
    const int G = (C + GS - 1) / GS;
    const int chunk = (N + C - 1) / C;
    int* chunk_hist = (int*)d_ws;
    int* Sg = chunk_hist + (size_t)C * NB;
    const size_t lds = rowbytes;
    const double invNB = 1.0 / (double)NB;

    k_bucket_hist<<<C, 256, lds, stream>>>(coords, seps, B, hash_op, N, NB, chunk,
                                           invNB, out_bucket, chunk_hist);
    dim3 g2a((NB + 255) / 256, G);
    k_scan_group<<<g2a, 256, 0, stream>>>(chunk_hist, Sg, C, NB);
    k_scan_tops<<<(NB + 255) / 256, 256, 0, stream>>>(Sg, G, NB, out_counts);
    k_gaps<<<NB, 64, 0, stream>>>(out_counts, out);
    k_scatter<<<C, 256, lds, stream>>>(coords, out_bucket, chunk_hist, Sg,
                                       N, NB, chunk, out);
}

// Round 5
// 225.333 us; speedup vs baseline: 1.1103x; 1.1103x over previous
//
#include <hip/hip_runtime.h>
#include <stdint.h>

#define PR1 73856093u
#define PR2 19349663u
#define PR3 83492791u
#define PR4 2654435761u
#define GS  32      // chunks per scan group
#define PPT 4       // points per thread per turn-round in k_scatter
#define BBITS 13    // bucket-id bits for ballot match (NB <= 8192)

// Branch-free uniform-divisor mod (exact for h < 2^32 via double).
__device__ __forceinline__ uint32_t fastmod(uint32_t h, uint32_t d, double inv) {
    uint32_t q = (uint32_t)((double)h * inv);
    int32_t r = (int32_t)(h - q * d);
    if (r >= (int32_t)d) r -= d;
    if (r < 0) r += d;
    return (uint32_t)r;
}

// K1: bucket per point (float out), per-chunk histogram -> chunk_hist[c][b].
// batch_id via incremental pointer (seps sorted, i monotone per thread).
__global__ void k_bucket_hist(const float* __restrict__ coords,
                              const int* __restrict__ seps, int B,
                              const int* __restrict__ hash_op_p,
                              int N, int NB, int chunk, double invNB,
                              float* __restrict__ out_bucket,
                              int* __restrict__ chunk_hist) {
    extern __shared__ int hist[];          // NB ints
    __shared__ int s_seps[1024];
    const int tid = threadIdx.x;
    for (int i = tid; i < NB; i += blockDim.x) hist[i] = 0;
    const int Bc = B < 1024 ? B : 1024;
    for (int j = tid; j < Bc; j += blockDim.x) s_seps[j] = seps[j];
    __syncthreads();

    const uint32_t hop = (uint32_t)hash_op_p[0];
    const int start = blockIdx.x * chunk;
    const int end   = min(start + chunk, N);
    int bid = 0;
    for (int i = start + tid; i < end; i += blockDim.x) {
        while (bid < B) {
            const int sv = (bid < 1024) ? s_seps[bid] : seps[bid];
            if (sv <= i) bid++; else break;
        }
        const float x = coords[3 * (size_t)i + 0];
        const float y = coords[3 * (size_t)i + 1];
        const float z = coords[3 * (size_t)i + 2];
        const uint32_t vx = (uint32_t)(int32_t)floorf(x);
        const uint32_t vy = (uint32_t)(int32_t)floorf(y);
        const uint32_t vz = (uint32_t)(int32_t)floorf(z);
        uint32_t h = vx * PR1 ^ vy * PR2 ^ vz * PR3 ^ ((uint32_t)bid * PR4);
        h += hop;
        const uint32_t b = fastmod(h, (uint32_t)NB, invNB);
        out_bucket[i] = (float)b;
        atomicAdd(&hist[(int)b], 1);
    }
    __syncthreads();
    int* dst = chunk_hist + (size_t)blockIdx.x * NB;
    for (int i = tid; i < NB; i += blockDim.x) dst[i] = hist[i];
}

// K2a: per bucket, exclusive scan within each group of GS chunks (in place);
// group totals -> Sg[g][b].
__global__ void k_scan_group(int* __restrict__ ch, int* __restrict__ Sg,
                             int C, int NB) {
    const int b = blockIdx.x * blockDim.x + threadIdx.x;
    if (b >= NB) return;
    const int g  = blockIdx.y;
    const int c0 = g * GS;
    const int c1 = min(c0 + GS, C);
    int run = 0;
    for (int c = c0; c < c1; c++) {
        const size_t idx = (size_t)c * NB + b;
        const int v = ch[idx];
        ch[idx] = run;
        run += v;
    }
    Sg[(size_t)g * NB + b] = run;
}

// K2b: exclusive scan over group totals (in place); total -> counts (float);
// fused gap-fill: zero out the unwritten slots [min(count,512),512) of this
// thread's bucket (replaces a separate 7813-block kernel / 48 MB memset).
__global__ void k_scan_tops(int* __restrict__ Sg, int G, int NB,
                            float* __restrict__ out_counts,
                            float* __restrict__ out_sc) {
    const int b = blockIdx.x * blockDim.x + threadIdx.x;
    if (b >= NB) return;
    int run = 0;
    for (int g = 0; g < G; g++) {
        const size_t idx = (size_t)g * NB + b;
        const int v = Sg[idx];
        Sg[idx] = run;
        run += v;
    }
    out_counts[b] = (float)run;
    const int c0 = run < 512 ? run : 512;
    float* p = out_sc + ((size_t)b * 512 + c0) * 3;
    for (int j = c0; j < 512; j++) {
        p[0] = 0.f; p[1] = 0.f; p[2] = 0.f;
        p += 3;
    }
}

// K3: stable within-bucket rank (arrival order) + scatter.
// Same-bucket lane groups found via BBITS ballot multi-split (13 iters, not 64).
__global__ __launch_bounds__(256, 4)
void k_scatter(const float* __restrict__ coords,
               const float* __restrict__ bucket_f,
               const int* __restrict__ ch,
               const int* __restrict__ Sg,
               int N, int NB, int chunk,
               float* __restrict__ out_sc) {
    extern __shared__ int hist[];          // NB running counters
    const int tid = threadIdx.x;
    const int c = blockIdx.x;
    const int g = c / GS;
    const int* r1 = ch + (size_t)c * NB;
    const int* r2 = Sg + (size_t)g * NB;
    for (int i = tid; i < NB; i += blockDim.x) hist[i] = r1[i] + r2[i];
    __syncthreads();

    const int start = c * chunk;
    const int end   = min(start + chunk, N);
    const int len   = end > start ? end - start : 0;
    const int per_round = (int)blockDim.x * PPT;     // 1024
    const int rounds = (len + per_round - 1) / per_round;
    const int lane = tid & 63;
    const int wv   = tid >> 6;
    const int nw   = (int)blockDim.x >> 6;
    const unsigned long long ltmask = ((unsigned long long)1 << lane) - 1;

    for (int rd = 0; rd < rounds; rd++) {
        const int wbase = start + rd * per_round + wv * (64 * PPT);
        int bs[PPT], leader[PPT], cntv[PPT], rnk[PPT];
        float cx[PPT], cy[PPT], cz[PPT];

        #pragma unroll
        for (int s = 0; s < PPT; s++) {
            const int i = wbase + s * 64 + lane;
            const bool v = (i < end);
            bs[s] = v ? (int)bucket_f[i] : NB;     // NB = sentinel, fits BBITS
            cx[s] = v ? coords[3 * (size_t)i + 0] : 0.f;
            cy[s] = v ? coords[3 * (size_t)i + 1] : 0.f;
            cz[s] = v ? coords[3 * (size_t)i + 2] : 0.f;
        }

        // Ballot multi-split: mm = mask of lanes with identical bucket id.
        #pragma unroll
        for (int s = 0; s < PPT; s++) {
            const int b = bs[s];
            unsigned long long mm = ~0ull;
            #pragma unroll
            for (int k = 0; k < BBITS; k++) {
                const unsigned long long blt = __ballot(((b >> k) & 1) != 0);
                mm &= ((b >> k) & 1) ? blt : ~blt;
            }
            leader[s] = (int)__builtin_ctzll(mm);
            cntv[s]   = (int)__builtin_popcountll(mm);
            rnk[s]    = (int)__builtin_popcountll(mm & ltmask);
        }

        // Wave turn loop: arrival order = wave 0..nw-1, sub-batch 0..PPT-1.
        int basev[PPT];
        for (int w = 0; w < nw; w++) {
            if (wv == w) {
                #pragma unroll
                for (int s = 0; s < PPT; s++) {
                    int old = 0;
                    if (bs[s] < NB && lane == leader[s])
                        old = atomicAdd(&hist[bs[s]], cntv[s]);
                    basev[s] = __shfl(old, leader[s], 64);
                }
            }
            __syncthreads();
        }

        #pragma unroll
        for (int s = 0; s < PPT; s++) {
            if (bs[s] < NB) {
                const int r = basev[s] + rnk[s];
                if (r < 512) {
                    float* p = out_sc + ((size_t)bs[s] * 512 + r) * 3;
                    p[0] = cx[s]; p[1] = cy[s]; p[2] = cz[s];
                }
            }
        }
    }
}

extern "C" void kernel_launch(void* const* d_in, const int* in_sizes, int n_in,
                              void* d_out, int out_size, void* d_ws, size_t ws_size,
                              hipStream_t stream) {
    const float* coords  = (const float*)d_in[0];
    const int*   seps    = (const int*)d_in[1];
    const int*   hash_op = (const int*)d_in[2];

    const int N = in_sizes[0] / 3;
    const int B = in_sizes[1];
    const int pad_to = ((N + 511) / 512) * 512;
    const int NB = pad_to / 512;

    float* out        = (float*)d_out;
    float* out_counts = out + (size_t)pad_to * 3;
    float* out_bucket = out_counts + NB;

    const size_t rowbytes = (size_t)NB * sizeof(int);
    const long rows = (long)(ws_size / rowbytes);
    int C = 1024;
    while (C > 1 && (long)(C + (C + GS - 1) / GS) > rows) C--;
    if (C < 1) C = 1;
    const int G = (C + GS - 1) / GS;
    const int chunk = (N + C - 1) / C;
    int* chunk_hist = (int*)d_ws;
    int* Sg = chunk_hist + (size_t)C * NB;
    const size_t lds = rowbytes;
    const double invNB = 1.0 / (double)NB;

    k_bucket_hist<<<C, 256, lds, stream>>>(coords, seps, B, hash_op, N, NB, chunk,
                                           invNB, out_bucket, chunk_hist);
    dim3 g2a((NB + 255) / 256, G);
    k_scan_group<<<g2a, 256, 0, stream>>>(chunk_hist, Sg, C, NB);
    k_scan_tops<<<(NB + 255) / 256, 256, 0, stream>>>(Sg, G, NB, out_counts, out);
    k_scatter<<<C, 256, lds, stream>>>(coords, out_bucket, chunk_hist, Sg,
                                       N, NB, chunk, out);
}

// Round 6
// 217.403 us; speedup vs baseline: 1.1508x; 1.0365x over previous
//
#include <hip/hip_runtime.h>
#include <stdint.h>

#define PR1 73856093u
#define PR2 19349663u
#define PR3 83492791u
#define PR4 2654435761u
#define GS  32      // chunks per scan group
#define PPT 4       // points per thread per turn-round in k_scatter
#define BBITS 13    // bucket-id bits for ballot match (NB <= 8192)

// Branch-free uniform-divisor mod (exact for h < 2^32 via double).
__device__ __forceinline__ uint32_t fastmod(uint32_t h, uint32_t d, double inv) {
    uint32_t q = (uint32_t)((double)h * inv);
    int32_t r = (int32_t)(h - q * d);
    if (r >= (int32_t)d) r -= d;
    if (r < 0) r += d;
    return (uint32_t)r;
}

// blockIdx -> chunk swizzle: give each XCD (blockIdx%8 under the default
// round-robin mapping) a CONTIGUOUS run of chunks, so rank-adjacent output
// lines are written from one XCD's L2 (RMW lines merge instead of bouncing
// between non-coherent per-XCD L2s). Pure performance heuristic: any
// bijection is correct.
__device__ __forceinline__ int chunk_of(int bi, int C) {
    return ((C & 7) == 0) ? ((bi & 7) * (C >> 3) + (bi >> 3)) : bi;
}

// K1: bucket per point (float out), per-chunk histogram (u16) -> ch[c][b].
__global__ void k_bucket_hist(const float* __restrict__ coords,
                              const int* __restrict__ seps, int B,
                              const int* __restrict__ hash_op_p,
                              int N, int NB, int C, int chunk, double invNB,
                              float* __restrict__ out_bucket,
                              uint16_t* __restrict__ ch) {
    extern __shared__ int hist[];          // NB ints
    __shared__ int s_seps[1024];
    const int tid = threadIdx.x;
    for (int i = tid; i < NB; i += blockDim.x) hist[i] = 0;
    const int Bc = B < 1024 ? B : 1024;
    for (int j = tid; j < Bc; j += blockDim.x) s_seps[j] = seps[j];
    __syncthreads();

    const uint32_t hop = (uint32_t)hash_op_p[0];
    const int c = chunk_of(blockIdx.x, C);
    const int start = c * chunk;
    const int end   = min(start + chunk, N);
    int bid = 0;                            // running searchsorted-right pointer
    for (int i = start + tid; i < end; i += blockDim.x) {
        while (bid < B) {
            const int sv = (bid < 1024) ? s_seps[bid] : seps[bid];
            if (sv <= i) bid++; else break;
        }
        const float x = coords[3 * (size_t)i + 0];
        const float y = coords[3 * (size_t)i + 1];
        const float z = coords[3 * (size_t)i + 2];
        const uint32_t vx = (uint32_t)(int32_t)floorf(x);
        const uint32_t vy = (uint32_t)(int32_t)floorf(y);
        const uint32_t vz = (uint32_t)(int32_t)floorf(z);
        uint32_t h = vx * PR1 ^ vy * PR2 ^ vz * PR3 ^ ((uint32_t)bid * PR4);
        h += hop;
        const uint32_t b = fastmod(h, (uint32_t)NB, invNB);
        out_bucket[i] = (float)b;
        atomicAdd(&hist[(int)b], 1);
    }
    __syncthreads();
    uint16_t* dst = ch + (size_t)c * NB;
    for (int i = tid; i < NB; i += blockDim.x) dst[i] = (uint16_t)hist[i];
}

// K2a: per bucket, exclusive scan within each group of GS chunks, stored
// CLAMPED at 512 (u16, in place); exact group totals -> Sg[g][b] (int).
// Clamp safety: if the true in-group base >= 512 the stored 512 still yields
// rank >= 512 -> dropped; below 512 the value is exact.
__global__ void k_scan_group(uint16_t* __restrict__ ch, int* __restrict__ Sg,
                             int C, int NB) {
    const int b = blockIdx.x * blockDim.x + threadIdx.x;
    if (b >= NB) return;
    const int g  = blockIdx.y;
    const int c0 = g * GS;
    const int c1 = min(c0 + GS, C);
    int run = 0;
    for (int c = c0; c < c1; c++) {
        const size_t idx = (size_t)c * NB + b;
        const int v = ch[idx];
        ch[idx] = (uint16_t)(run < 512 ? run : 512);
        run += v;
    }
    Sg[(size_t)g * NB + b] = run;
}

// K2b: exclusive scan over group totals (int, exact, in place); total ->
// counts (float); fused gap-fill of unwritten slots [min(count,512),512).
__global__ void k_scan_tops(int* __restrict__ Sg, int G, int NB,
                            float* __restrict__ out_counts,
                            float* __restrict__ out_sc) {
    const int b = blockIdx.x * blockDim.x + threadIdx.x;
    if (b >= NB) return;
    int run = 0;
    for (int g = 0; g < G; g++) {
        const size_t idx = (size_t)g * NB + b;
        const int v = Sg[idx];
        Sg[idx] = run;
        run += v;
    }
    out_counts[b] = (float)run;
    const int c0 = run < 512 ? run : 512;
    float* p = out_sc + ((size_t)b * 512 + c0) * 3;
    for (int j = c0; j < 512; j++) {
        p[0] = 0.f; p[1] = 0.f; p[2] = 0.f;
        p += 3;
    }
}

// K3: stable within-bucket rank (arrival order) + scatter.
// Same-bucket lane groups via BBITS ballot multi-split (13 iters).
__global__ __launch_bounds__(256, 4)
void k_scatter(const float* __restrict__ coords,
               const float* __restrict__ bucket_f,
               const uint16_t* __restrict__ ch,
               const int* __restrict__ Sg,
               int N, int NB, int C, int chunk,
               float* __restrict__ out_sc) {
    extern __shared__ int hist[];          // NB running counters
    const int tid = threadIdx.x;
    const int c = chunk_of(blockIdx.x, C);
    const int g = c / GS;
    const uint16_t* r1 = ch + (size_t)c * NB;
    const int*      r2 = Sg + (size_t)g * NB;
    for (int i = tid; i < NB; i += blockDim.x) hist[i] = (int)r1[i] + r2[i];
    __syncthreads();

    const int start = c * chunk;
    const int end   = min(start + chunk, N);
    const int len   = end > start ? end - start : 0;
    const int per_round = (int)blockDim.x * PPT;     // 1024
    const int rounds = (len + per_round - 1) / per_round;
    const int lane = tid & 63;
    const int wv   = tid >> 6;
    const int nw   = (int)blockDim.x >> 6;
    const unsigned long long ltmask = ((unsigned long long)1 << lane) - 1;

    for (int rd = 0; rd < rounds; rd++) {
        const int wbase = start + rd * per_round + wv * (64 * PPT);
        int bs[PPT], leader[PPT], cntv[PPT], rnk[PPT];
        float cx[PPT], cy[PPT], cz[PPT];

        #pragma unroll
        for (int s = 0; s < PPT; s++) {
            const int i = wbase + s * 64 + lane;
            const bool v = (i < end);
            bs[s] = v ? (int)bucket_f[i] : NB;     // NB = sentinel, fits BBITS
            cx[s] = v ? coords[3 * (size_t)i + 0] : 0.f;
            cy[s] = v ? coords[3 * (size_t)i + 1] : 0.f;
            cz[s] = v ? coords[3 * (size_t)i + 2] : 0.f;
        }

        // Ballot multi-split: mm = mask of lanes with identical bucket id.
        #pragma unroll
        for (int s = 0; s < PPT; s++) {
            const int b = bs[s];
            unsigned long long mm = ~0ull;
            #pragma unroll
            for (int k = 0; k < BBITS; k++) {
                const unsigned long long blt = __ballot(((b >> k) & 1) != 0);
                mm &= ((b >> k) & 1) ? blt : ~blt;
            }
            leader[s] = (int)__builtin_ctzll(mm);
            cntv[s]   = (int)__builtin_popcountll(mm);
            rnk[s]    = (int)__builtin_popcountll(mm & ltmask);
        }

        // Wave turn loop: arrival order = wave 0..nw-1, sub-batch 0..PPT-1.
        int basev[PPT];
        for (int w = 0; w < nw; w++) {
            if (wv == w) {
                #pragma unroll
                for (int s = 0; s < PPT; s++) {
                    int old = 0;
                    if (bs[s] < NB && lane == leader[s])
                        old = atomicAdd(&hist[bs[s]], cntv[s]);
                    basev[s] = __shfl(old, leader[s], 64);
                }
            }
            __syncthreads();
        }

        #pragma unroll
        for (int s = 0; s < PPT; s++) {
            if (bs[s] < NB) {
                const int r = basev[s] + rnk[s];
                if (r < 512) {
                    float* p = out_sc + ((size_t)bs[s] * 512 + r) * 3;
                    p[0] = cx[s]; p[1] = cy[s]; p[2] = cz[s];
                }
            }
        }
    }
}

extern "C" void kernel_launch(void* const* d_in, const int* in_sizes, int n_in,
                              void* d_out, int out_size, void* d_ws, size_t ws_size,
                              hipStream_t stream) {
    const float* coords  = (const float*)d_in[0];
    const int*   seps    = (const int*)d_in[1];
    const int*   hash_op = (const int*)d_in[2];

    const int N = in_sizes[0] / 3;
    const int B = in_sizes[1];
    const int pad_to = ((N + 511) / 512) * 512;
    const int NB = pad_to / 512;

    float* out        = (float*)d_out;
    float* out_counts = out + (size_t)pad_to * 3;
    float* out_bucket = out_counts + NB;

    // Workspace: ch (u16, C x NB) then Sg (int, G x NB).
    int C = 1024;
    while (C > 8) {
        const int G_ = (C + GS - 1) / GS;
        if ((size_t)C * NB * 2 + (size_t)G_ * NB * 4 <= ws_size) break;
        C -= 8;
    }
    const int G = (C + GS - 1) / GS;
    const int chunk = (N + C - 1) / C;
    uint16_t* ch = (uint16_t*)d_ws;
    int* Sg = (int*)((char*)d_ws + (((size_t)C * NB * 2 + 15) & ~(size_t)15));
    const size_t lds = (size_t)NB * sizeof(int);
    const double invNB = 1.0 / (double)NB;

    k_bucket_hist<<<C, 256, lds, stream>>>(coords, seps, B, hash_op, N, NB, C,
                                           chunk, invNB, out_bucket, ch);
    dim3 g2a((NB + 255) / 256, G);
    k_scan_group<<<g2a, 256, 0, stream>>>(ch, Sg, C, NB);
    k_scan_tops<<<(NB + 255) / 256, 256, 0, stream>>>(Sg, G, NB, out_counts, out);
    k_scatter<<<C, 256, lds, stream>>>(coords, out_bucket, ch, Sg,
                                       N, NB, C, chunk, out);
}